// Round 4
// baseline (423.426 us; speedup 1.0000x reference)
//
#include <hip/hip_runtime.h>
#include <math.h>

#define BB 16
#define II 1024
#define HH 2048

// One block per output unit o (2048 blocks, 256 thr = 4 waves).
// exp(W_hh[o,:]*mask/tau) and W_ih_w[o,:] are computed/loaded ONCE into
// registers and reused across all 16 batches (wave w handles b = 4i+w).
// exp(gumbel(u)) = 1/L with L = eps - log(u+eps), so e = Q/L -- no exp in the
// hot loop. No softmax max-shift: Q in [~0.89,1.13], 1/L <= ~1e8, row sum
// < 1e9 -- fp32-safe; shift cancels in t/s (verified: absmax 4.9e-4 in R3).
// Traffic: gumbel 256 MiB (streamed once) + W_hh/mask/W_ih one-shot ~42 MB;
// h_prev/x_t (192 KB) L2-resident. ~300 MB => ~47 us HBM floor.
__global__ __launch_bounds__(256, 4) void reservoir_cell_kernel(
    const float* __restrict__ x_t,        // (B, I)
    const float* __restrict__ h_prev,     // (B, H)
    const float* __restrict__ W_ih_w,     // (H, I)
    const float* __restrict__ W_ih_b,     // (H,)
    const float* __restrict__ W_hh,       // (H, H)
    const float* __restrict__ hh_mask,    // (H, H)
    const float* __restrict__ temperature,// (1,)
    const float* __restrict__ gumbel,     // (B, H, H)
    float* __restrict__ out)              // (B, H)
{
    const int o    = blockIdx.x;          // 0..2047
    const int wave = threadIdx.x >> 6;    // 0..3
    const int lane = threadIdx.x & 63;

    const float tau     = fmaxf(temperature[0], 1e-3f);
    const float inv_tau = 1.0f / tau;

    // ---- persistent per-lane registers: Q row (32 VGPR) + W_ih row (16 VGPR)
    const float4* wh4 = (const float4*)(W_hh   + (size_t)o * HH);
    const float4* mk4 = (const float4*)(hh_mask+ (size_t)o * HH);
    float4 Q[8];
    #pragma unroll
    for (int j = 0; j < 8; ++j) {
        float4 w = wh4[j * 64 + lane];
        float4 m = mk4[j * 64 + lane];
        Q[j].x = __expf(w.x * m.x * inv_tau);
        Q[j].y = __expf(w.y * m.y * inv_tau);
        Q[j].z = __expf(w.z * m.z * inv_tau);
        Q[j].w = __expf(w.w * m.w * inv_tau);
    }
    const float4* wi4 = (const float4*)(W_ih_w + (size_t)o * II);
    float4 Wi[4];
    #pragma unroll
    for (int j = 0; j < 4; ++j) Wi[j] = wi4[j * 64 + lane];

    const float bias = W_ih_b[o];

    // ---- 4 batches per wave, sequential (keep register pressure flat) ----
    #pragma unroll 1
    for (int i = 0; i < 4; ++i) {
        const int b = (i << 2) + wave;    // 0..15

        // input contribution: dot(x_t[b,:], W_ih_w[o,:])
        const float4* x4 = (const float4*)(x_t + (size_t)b * II);
        float ic = 0.0f;
        #pragma unroll
        for (int j = 0; j < 4; ++j) {
            float4 xv = x4[j * 64 + lane];
            ic += xv.x * Wi[j].x + xv.y * Wi[j].y + xv.z * Wi[j].z + xv.w * Wi[j].w;
        }

        // streaming: L = eps - log(u+eps); e = Q/L; s += e; t += e*h_prev
        const float4* g4 = (const float4*)(gumbel + ((size_t)b * HH + o) * HH);
        const float4* p4 = (const float4*)(h_prev + (size_t)b * HH);
        float s = 0.0f, t = 0.0f;
        #pragma unroll 4
        for (int j = 0; j < 8; ++j) {
            float4 u  = g4[j * 64 + lane];
            float4 hv = p4[j * 64 + lane];
            float L, e;
            L = 1e-10f - __logf(u.x + 1e-10f); e = Q[j].x * __builtin_amdgcn_rcpf(L); s += e; t += e * hv.x;
            L = 1e-10f - __logf(u.y + 1e-10f); e = Q[j].y * __builtin_amdgcn_rcpf(L); s += e; t += e * hv.y;
            L = 1e-10f - __logf(u.z + 1e-10f); e = Q[j].z * __builtin_amdgcn_rcpf(L); s += e; t += e * hv.z;
            L = 1e-10f - __logf(u.w + 1e-10f); e = Q[j].w * __builtin_amdgcn_rcpf(L); s += e; t += e * hv.w;
        }

        // wave reductions (ic, s, t)
        #pragma unroll
        for (int off = 32; off; off >>= 1) {
            ic += __shfl_down(ic, off, 64);
            s  += __shfl_down(s,  off, 64);
            t  += __shfl_down(t,  off, 64);
        }

        if (lane == 0) {
            out[(size_t)b * HH + o] = tanhf(ic + bias + t / s);
        }
    }
}

extern "C" void kernel_launch(void* const* d_in, const int* in_sizes, int n_in,
                              void* d_out, int out_size, void* d_ws, size_t ws_size,
                              hipStream_t stream) {
    const float* x_t         = (const float*)d_in[0];
    const float* h_prev      = (const float*)d_in[1];
    const float* W_ih_w      = (const float*)d_in[2];
    const float* W_ih_b      = (const float*)d_in[3];
    const float* W_hh        = (const float*)d_in[4];
    const float* hh_mask     = (const float*)d_in[5];
    const float* temperature = (const float*)d_in[6];
    const float* gumbel      = (const float*)d_in[7];
    float* out = (float*)d_out;

    reservoir_cell_kernel<<<dim3(HH), dim3(256), 0, stream>>>(
        x_t, h_prev, W_ih_w, W_ih_b, W_hh, hh_mask, temperature, gumbel, out);
}